// Round 5
// baseline (156.247 us; speedup 1.0000x reference)
//
#include <hip/hip_runtime.h>
#include <stdint.h>

// Fused BSQ: recon = sign(x @ Wp + bp) @ Wr + br   (L2-normalize is sign-invariant)
// x: [65536][512] f32, Wp: [512][16], bp: [16], Wr: [16][512], br: [512]
//
// Round-5: x never touches VGPRs. Each wave stages ITS OWN 512B/row c-slice
// into an 8-slot LDS ring via global_load_lds (width 4), gated by per-wave
// counted s_waitcnt vmcnt(14) — no barriers in phase 1, depth-8 pipeline
// (~1600 cyc issue->use) hides HBM/L3 latency. Round-4 failure mode (compiler
// sinking register prefetches, VGPR=76 proved it) is structurally impossible:
// a DMA op can't be sunk into its LDS consumer across "memory" asm.
// Lane (w = c-quarter, cg, dg): c = w*128 + j*16 + cg*4 + e  (bank-conflict-
// free ds_read_b128: 4 distinct addrs per j hit disjoint bank quads; the 16
// dg-lanes broadcast). Phase 2 (after ONE lgkm-only barrier): zp quad read,
// ballot -> mask in-register, VALU recon, streaming store. Rare (~2%,
// block-uniform) exact-f64 redo (reference signs are f64-exact: rounds 1-4
// absmax 0.0).

#define ROWS    65536
#define TILE    32
#define BLOCKS  (ROWS / TILE)   // 2048
#define TAU     1e-3f
#define DPTH    8               // rows in flight per wave

#define BAR()    asm volatile("s_waitcnt lgkmcnt(0)\n\ts_barrier" ::: "memory")
#define WAITV(N) asm volatile("s_waitcnt vmcnt(" #N ")" ::: "memory")
#define WAITL()  asm volatile("s_waitcnt lgkmcnt(0)" ::: "memory")

typedef const __attribute__((address_space(1))) void* gas1_t;
typedef __attribute__((address_space(3))) void*       las3_t;

__global__ __launch_bounds__(256, 4)
void bsq_fused(const float* __restrict__ x,
               const float* __restrict__ Wp,
               const float* __restrict__ bp,
               const float* __restrict__ Wr,
               const float* __restrict__ br,
               float* __restrict__ out)
{
    const int tid = threadIdx.x;
    const int w   = tid >> 6;      // wave 0..3: c-quarter
    const int l   = tid & 63;
    const int cg  = l >> 4;        // 0..3
    const int dg  = l & 15;        // 0..15: this lane's d

    __shared__ __align__(16) float  xl[DPTH * 512];   // 16 KB x ring
    __shared__ __align__(16) float  zp[TILE][16][4];  // 8 KB partials
    __shared__ __align__(16) double zb64[16][4];      // rare exact path

    // ---- weights into registers FIRST (oldest VMEM ops -> drained by the
    //      first WAITV(14); nothing interleaves into the stage stream) ----
    float wp[32];                  // wp[4j+e] = Wp[w*128 + j*16 + cg*4 + e][dg]
#pragma unroll
    for (int j = 0; j < 8; ++j)
#pragma unroll
        for (int e = 0; e < 4; ++e)
            wp[4 * j + e] = Wp[(w * 128 + j * 16 + cg * 4 + e) * 16 + dg];

    float2 wr2[16];                // Wr[d][tid*2 .. +1]
    const float2* Wr2 = (const float2*)Wr;
#pragma unroll
    for (int d = 0; d < 16; ++d) wr2[d] = Wr2[d * 256 + tid];
    const float2 br2v = ((const float2*)br)[tid];
    const float  bpf  = bp[dg];
    const double bpd  = (double)bpf;

    const int    row0 = blockIdx.x * TILE;
    const float* xsrc = x + (size_t)row0 * 512 + w * 128 + l;  // per-lane src

    // stage local row r: wave w copies its own 512B slice (2x 256B DMA)
    auto stage = [&](int r) {
        const int slot = r & (DPTH - 1);
        const float* s = xsrc + (size_t)r * 512;
        __builtin_amdgcn_global_load_lds((gas1_t)(s),
            (las3_t)(&xl[slot * 512 + w * 128]), 4, 0, 0);
        __builtin_amdgcn_global_load_lds((gas1_t)(s + 64),
            (las3_t)(&xl[slot * 512 + w * 128 + 64]), 4, 0, 0);
    };

    auto compute_row = [&](int r, bool do_stage) {
        const int slot = r & (DPTH - 1);
        const float* base = &xl[slot * 512 + w * 128 + cg * 4];
        float4 xr[8];
#pragma unroll
        for (int j = 0; j < 8; ++j)
            xr[j] = *(const float4*)(base + j * 16);
        WAITL();                       // ds_reads done -> slot safe to rewrite
        if (do_stage) stage(r + DPTH); // lands >= 8 iters before its use

        float a0 = 0.f, a1 = 0.f, a2 = 0.f, a3 = 0.f;
#pragma unroll
        for (int j = 0; j < 8; ++j) {
            a0 = fmaf(xr[j].x, wp[4 * j + 0], a0);
            a1 = fmaf(xr[j].y, wp[4 * j + 1], a1);
            a2 = fmaf(xr[j].z, wp[4 * j + 2], a2);
            a3 = fmaf(xr[j].w, wp[4 * j + 3], a3);
        }
        float a = (a0 + a1) + (a2 + a3);
        a += __shfl_xor(a, 16, 64);    // reduce over cg (lane bits 4,5)
        a += __shfl_xor(a, 32, 64);
        if (cg == 0) zp[r][dg][w] = a;
    };

    // ================= Phase 1: signs (NO barriers) =================
#pragma unroll
    for (int r = 0; r < DPTH; ++r) stage(r);

#pragma unroll 1
    for (int r = 0; r < TILE - DPTH; ++r) {   // r = 0..23
        WAITV(14);                 // rows r+1..r+7 (14 loads) stay in flight
        compute_row(r, true);
    }
    // tail: in-flight shrinks by 2 loads per row
    WAITV(14); compute_row(24, false);
    WAITV(12); compute_row(25, false);
    WAITV(10); compute_row(26, false);
    WAITV(8);  compute_row(27, false);
    WAITV(6);  compute_row(28, false);
    WAITV(4);  compute_row(29, false);
    WAITV(2);  compute_row(30, false);
    WAITV(0);  compute_row(31, false);

    BAR();   // zp visible to all waves (lgkm-only; nothing left in vmcnt)

    // ================= Phase 2: reduce + recon (no barriers) =================
#pragma unroll 2
    for (int r = 0; r < TILE; ++r) {
        const int row = row0 + r;

        const float4 q = *reinterpret_cast<const float4*>(&zp[r][dg][0]);
        const float  z = (q.x + q.y) + (q.z + q.w) + bpf;

        bool sgn = (z >= 0.0f);
        // block-uniform predicate (z depends only on dg): barriers inside match
        const unsigned long long amb = __ballot(fabsf(z) < TAU);
        if (amb) {
            const float* xp = x + (size_t)row * 512 + w * 128 + cg * 4;
            double ad = 0.0;
#pragma unroll
            for (int j = 0; j < 8; ++j) {
                const float4 xf = *(const float4*)(xp + j * 16);
                ad = fma((double)xf.x, (double)wp[4 * j + 0], ad);
                ad = fma((double)xf.y, (double)wp[4 * j + 1], ad);
                ad = fma((double)xf.z, (double)wp[4 * j + 2], ad);
                ad = fma((double)xf.w, (double)wp[4 * j + 3], ad);
            }
            ad += __shfl_xor(ad, 16, 64);
            ad += __shfl_xor(ad, 32, 64);
            if (cg == 0) zb64[dg][w] = ad;
            BAR();
            const double zd = (zb64[dg][0] + zb64[dg][1])
                            + (zb64[dg][2] + zb64[dg][3]) + bpd;
            sgn = (zd >= 0.0);
            BAR();   // reads done before any future zb64 rewrite
        }

        const unsigned long long bits = __ballot(sgn);  // bits 0..15 = d 0..15
        const int m = (int)(bits & 0xFFFFull);

        float ox = br2v.x, oy = br2v.y;
#pragma unroll
        for (int d = 0; d < 16; ++d) {
            const float s = ((m >> d) & 1) ? 1.0f : -1.0f;
            ox = fmaf(s, wr2[d].x, ox);
            oy = fmaf(s, wr2[d].y, oy);
        }
        ((float2*)out)[(size_t)row * 256 + tid] = make_float2(ox, oy);
    }
}

extern "C" void kernel_launch(void* const* d_in, const int* in_sizes, int n_in,
                              void* d_out, int out_size, void* d_ws, size_t ws_size,
                              hipStream_t stream) {
    const float* x  = (const float*)d_in[0];
    const float* Wp = (const float*)d_in[1];
    const float* bp = (const float*)d_in[2];
    const float* Wr = (const float*)d_in[3];
    const float* br = (const float*)d_in[4];
    float* out = (float*)d_out;

    bsq_fused<<<BLOCKS, 256, 0, stream>>>(x, Wp, bp, Wr, br, out);
}

// Round 6
// 76.881 us; speedup vs baseline: 2.0323x; 2.0323x over previous
//
#include <hip/hip_runtime.h>
#include <stdint.h>

// Fused BSQ: recon = sign(x @ Wp + bp) @ Wr + br   (L2-normalize is sign-invariant)
// x: [65536][512] f32, Wp: [512][16], bp: [16], Wr: [16][512], br: [512]
//
// Round-6 = round-5 pipeline minus the spill:
//   - x staged via global_load_lds 8-row ring, per-wave counted vmcnt(14),
//     zero barriers in phase 1 (HBM latency hidden by depth-8 + TLP).
//   - __launch_bounds__(256,2): round-5's (256,4) pinned VGPR=64 and spilled
//     24 MB of scratch (WRITE_SIZE 155648 vs 131072 KB proved it).
//   - Register lifetimes phase-disjoint: wp[32] dies at end of phase 1 (rare
//     f64 path reloads it from L2-hot Wp); wr2[32]/br2v load after the
//     barrier. Peak ~95 VGPR -> 4 waves/SIMD, no spill.
//   - Reference signs are f64-exact: rounds 1-5 absmax 0.0.

#define ROWS    65536
#define TILE    32
#define BLOCKS  (ROWS / TILE)   // 2048
#define TAU     1e-3f
#define DPTH    8               // rows in flight per wave

#define BAR()    asm volatile("s_waitcnt lgkmcnt(0)\n\ts_barrier" ::: "memory")
#define WAITV(N) asm volatile("s_waitcnt vmcnt(" #N ")" ::: "memory")
#define WAITL()  asm volatile("s_waitcnt lgkmcnt(0)" ::: "memory")

typedef const __attribute__((address_space(1))) void* gas1_t;
typedef __attribute__((address_space(3))) void*       las3_t;

__global__ __launch_bounds__(256, 2)
void bsq_fused(const float* __restrict__ x,
               const float* __restrict__ Wp,
               const float* __restrict__ bp,
               const float* __restrict__ Wr,
               const float* __restrict__ br,
               float* __restrict__ out)
{
    const int tid = threadIdx.x;
    const int w   = tid >> 6;      // wave 0..3: c-quarter
    const int l   = tid & 63;
    const int cg  = l >> 4;        // 0..3
    const int dg  = l & 15;        // 0..15: this lane's d

    __shared__ __align__(16) float  xl[DPTH * 512];   // 16 KB x ring
    __shared__ __align__(16) float  zp[TILE][16][4];  // 8 KB partials
    __shared__ __align__(16) double zb64[16][4];      // rare exact path

    // ---- phase-1 weights (all VMEM issued before the first counted wait) ----
    float wp[32];                  // wp[4j+e] = Wp[w*128 + j*16 + cg*4 + e][dg]
#pragma unroll
    for (int j = 0; j < 8; ++j)
#pragma unroll
        for (int e = 0; e < 4; ++e)
            wp[4 * j + e] = Wp[(w * 128 + j * 16 + cg * 4 + e) * 16 + dg];
    const float  bpf = bp[dg];
    const double bpd = (double)bpf;

    const int    row0 = blockIdx.x * TILE;
    const float* xsrc = x + (size_t)row0 * 512 + w * 128 + l;  // per-lane src

    // stage local row r: wave w DMAs its own 512B slice (2x 256B)
    auto stage = [&](int r) {
        const int slot = r & (DPTH - 1);
        const float* s = xsrc + (size_t)r * 512;
        __builtin_amdgcn_global_load_lds((gas1_t)(s),
            (las3_t)(&xl[slot * 512 + w * 128]), 4, 0, 0);
        __builtin_amdgcn_global_load_lds((gas1_t)(s + 64),
            (las3_t)(&xl[slot * 512 + w * 128 + 64]), 4, 0, 0);
    };

    auto compute_row = [&](int r, bool do_stage) {
        const int slot = r & (DPTH - 1);
        const float* base = &xl[slot * 512 + w * 128 + cg * 4];
        float4 xr[8];
#pragma unroll
        for (int j = 0; j < 8; ++j)
            xr[j] = *(const float4*)(base + j * 16);

        float a0 = 0.f, a1 = 0.f, a2 = 0.f, a3 = 0.f;
#pragma unroll
        for (int j = 0; j < 8; ++j) {            // compiler interleaves
            a0 = fmaf(xr[j].x, wp[4 * j + 0], a0);  // fine-grained lgkm waits
            a1 = fmaf(xr[j].y, wp[4 * j + 1], a1);
            a2 = fmaf(xr[j].z, wp[4 * j + 2], a2);
            a3 = fmaf(xr[j].w, wp[4 * j + 3], a3);
        }
        WAITL();                       // all ds_reads retired -> slot reusable
        if (do_stage) stage(r + DPTH); // lands ~8 rows ahead of its use

        float a = (a0 + a1) + (a2 + a3);
        a += __shfl_xor(a, 16, 64);    // reduce over cg (lane bits 4,5)
        a += __shfl_xor(a, 32, 64);
        if (cg == 0) zp[r][dg][w] = a;
    };

    // ================= Phase 1: signs (NO barriers) =================
#pragma unroll
    for (int r = 0; r < DPTH; ++r) stage(r);

#pragma unroll 1
    for (int r = 0; r < TILE - DPTH; ++r) {   // r = 0..23
        WAITV(14);                 // drain row r's 2 loads; 7 rows in flight
        compute_row(r, true);
    }
    WAITV(14); compute_row(24, false);
    WAITV(12); compute_row(25, false);
    WAITV(10); compute_row(26, false);
    WAITV(8);  compute_row(27, false);
    WAITV(6);  compute_row(28, false);
    WAITV(4);  compute_row(29, false);
    WAITV(2);  compute_row(30, false);
    WAITV(0);  compute_row(31, false);

    BAR();   // zp visible to all waves (lgkm-only; vmcnt already 0)

    // ---- phase-2 weights (wp is dead now; disjoint register lifetime) ----
    float2 wr2[16];                // Wr[d][tid*2 .. +1]
    const float2* Wr2 = (const float2*)Wr;
#pragma unroll
    for (int d = 0; d < 16; ++d) wr2[d] = Wr2[d * 256 + tid];
    const float2 br2v = ((const float2*)br)[tid];

    // ================= Phase 2: reduce + recon (no barriers) =================
#pragma unroll 2
    for (int r = 0; r < TILE; ++r) {
        const int row = row0 + r;

        const float4 q = *reinterpret_cast<const float4*>(&zp[r][dg][0]);
        const float  z = (q.x + q.y) + (q.z + q.w) + bpf;

        bool sgn = (z >= 0.0f);
        // block-uniform predicate (z depends only on dg): barriers inside match
        const unsigned long long amb = __ballot(fabsf(z) < TAU);
        if (amb) {
            // rare (~2% of rows): exact-f64 redo; reload x row AND wp slice
            // (both L2/L3-hot) so wp needn't stay live in phase 2.
            const float* xp = x + (size_t)row * 512 + w * 128 + cg * 4;
            double ad = 0.0;
#pragma unroll
            for (int j = 0; j < 8; ++j) {
                const float4 xf = *(const float4*)(xp + j * 16);
#pragma unroll
                for (int e = 0; e < 4; ++e) {
                    const float wpe = Wp[(w * 128 + j * 16 + cg * 4 + e) * 16 + dg];
                    const float xe  = e == 0 ? xf.x : e == 1 ? xf.y
                                   : e == 2 ? xf.z : xf.w;
                    ad = fma((double)xe, (double)wpe, ad);
                }
            }
            ad += __shfl_xor(ad, 16, 64);
            ad += __shfl_xor(ad, 32, 64);
            if (cg == 0) zb64[dg][w] = ad;
            BAR();
            const double zd = (zb64[dg][0] + zb64[dg][1])
                            + (zb64[dg][2] + zb64[dg][3]) + bpd;
            sgn = (zd >= 0.0);
            BAR();   // reads done before any future zb64 rewrite
        }

        const unsigned long long bits = __ballot(sgn);  // bits 0..15 = d 0..15
        const int m = (int)(bits & 0xFFFFull);

        float ox = br2v.x, oy = br2v.y;
#pragma unroll
        for (int d = 0; d < 16; ++d) {
            const float s = ((m >> d) & 1) ? 1.0f : -1.0f;
            ox = fmaf(s, wr2[d].x, ox);
            oy = fmaf(s, wr2[d].y, oy);
        }
        ((float2*)out)[(size_t)row * 256 + tid] = make_float2(ox, oy);
    }
}

extern "C" void kernel_launch(void* const* d_in, const int* in_sizes, int n_in,
                              void* d_out, int out_size, void* d_ws, size_t ws_size,
                              hipStream_t stream) {
    const float* x  = (const float*)d_in[0];
    const float* Wp = (const float*)d_in[1];
    const float* bp = (const float*)d_in[2];
    const float* Wr = (const float*)d_in[3];
    const float* br = (const float*)d_in[4];
    float* out = (float*)d_out;

    bsq_fused<<<BLOCKS, 256, 0, stream>>>(x, Wp, bp, Wr, br, out);
}

// Round 7
// 75.208 us; speedup vs baseline: 2.0775x; 1.0222x over previous
//
#include <hip/hip_runtime.h>
#include <stdint.h>

// Fused BSQ: recon = sign(x @ Wp + bp) @ Wr + br   (L2-normalize is sign-invariant)
// x: [65536][512] f32, Wp: [512][16], bp: [16], Wr: [16][512], br: [512]
//
// Round-7: cut the per-row serial latency that round 6 left behind.
//  - Paired-row ring slots: ONE width-16 global_load_lds stages 2 rows/wave
//    (1 KB); ring = 4 slots (8 rows, 16 KB). vmcnt = 1 instr/slot -> WAITV(3).
//  - 2-row chunks between asm fences: the two dot+reduce chains overlap.
//  - ONE shfl_xor per row (cg-pair reduce); 2 partials/row -> zp[32][16][8];
//    phase 2 does the final 8-way add from LDS (throughput, not latency).
//  - Phase 2 is BARRIER-FREE: ambiguous rows (|z|<TAU, ~2%) go into a
//    block-uniform bitmask; a post-loop uniform fixup loop redoes them in
//    exact f64 (matched barriers by construction) and overwrites the
//    provisional stores. Kills rounds 4-6's latent barrier-in-divergent-loop
//    hazard. Reference signs are f64-exact: rounds 1-6 absmax 0.0.

#define ROWS   65536
#define TILE   32
#define BLOCKS (ROWS / TILE)   // 2048
#define TAU    1e-3f
#define RING   4               // slots of 2 rows each (8 rows in flight)

#define BAR()    asm volatile("s_waitcnt lgkmcnt(0)\n\ts_barrier" ::: "memory")
#define WAITV(N) asm volatile("s_waitcnt vmcnt(" #N ")" ::: "memory")
#define WAITL()  asm volatile("s_waitcnt lgkmcnt(0)" ::: "memory")

typedef const __attribute__((address_space(1))) void* gas1_t;
typedef __attribute__((address_space(3))) void*       las3_t;

__global__ __launch_bounds__(256, 2)
void bsq_fused(const float* __restrict__ x,
               const float* __restrict__ Wp,
               const float* __restrict__ bp,
               const float* __restrict__ Wr,
               const float* __restrict__ br,
               float* __restrict__ out)
{
    const int tid = threadIdx.x;
    const int w   = tid >> 6;      // wave 0..3: c-quarter
    const int l   = tid & 63;
    const int cg  = l >> 4;        // 0..3
    const int dg  = l & 15;        // 0..15: this lane's d

    __shared__ __align__(16) float  xl[RING * 1024];   // 16 KB: [slot][w][p][128]
    __shared__ __align__(16) float  zp[TILE][16][8];   // 16 KB: 8 partials/row/d
    __shared__ __align__(16) double zb64[16][4];       // fixup exchange

    // ---- phase-1 weights (drained by chunk-0's WAITV(0), order-robust) ----
    float wp[32];                  // wp[4j+e] = Wp[w*128 + j*16 + cg*4 + e][dg]
#pragma unroll
    for (int j = 0; j < 8; ++j)
#pragma unroll
        for (int e = 0; e < 4; ++e)
            wp[4 * j + e] = Wp[(w * 128 + j * 16 + cg * 4 + e) * 16 + dg];
    const float  bpf = bp[dg];
    const double bpd = (double)bpf;

    const int row0 = blockIdx.x * TILE;
    // lane's staging source: lane l covers row parity (l>>5), floats (l&31)*4..+3
    const float* xsrc = x + (size_t)row0 * 512 + (size_t)(l >> 5) * 512
                          + w * 128 + (l & 31) * 4;

    auto stage_slot = [&](int s) {    // stage rows 2s, 2s+1 (1 KB, one dwordx4 DMA)
        __builtin_amdgcn_global_load_lds(
            (gas1_t)(xsrc + (size_t)(2 * s) * 512),
            (las3_t)(&xl[(s & (RING - 1)) * 1024 + w * 256]), 16, 0, 0);
    };

    auto dot_row = [&](int s, int p) {
        const float* base = &xl[(s & (RING - 1)) * 1024 + w * 256 + p * 128 + cg * 4];
        float4 xr[8];
#pragma unroll
        for (int j = 0; j < 8; ++j) xr[j] = *(const float4*)(base + j * 16);
        float a0 = 0.f, a1 = 0.f, a2 = 0.f, a3 = 0.f;
#pragma unroll
        for (int j = 0; j < 8; ++j) {
            a0 = fmaf(xr[j].x, wp[4 * j + 0], a0);
            a1 = fmaf(xr[j].y, wp[4 * j + 1], a1);
            a2 = fmaf(xr[j].z, wp[4 * j + 2], a2);
            a3 = fmaf(xr[j].w, wp[4 * j + 3], a3);
        }
        float a = (a0 + a1) + (a2 + a3);
        a += __shfl_xor(a, 16, 64);            // combine cg pairs {0,1},{2,3}
        if ((l & 16) == 0)                     // cg even: one writer per pair
            zp[2 * s + p][dg][w * 2 + (cg >> 1)] = a;
    };

    // ================= Phase 1: signs (no barriers) =================
#pragma unroll
    for (int s = 0; s < RING; ++s) stage_slot(s);

    // chunk 0: full drain (robust vs any wp/stage issue-order interleave)
    WAITV(0); dot_row(0, 0); dot_row(0, 1); WAITL(); stage_slot(4);
#pragma unroll 1
    for (int s = 1; s < 12; ++s) {
        WAITV(3);                  // oldest slot's DMA retired -> data in LDS
        dot_row(s, 0); dot_row(s, 1);
        WAITL();                   // slot's ds_reads retired -> safe to rewrite
        stage_slot(s + 4);
    }
    WAITV(3); dot_row(12, 0); dot_row(12, 1);
    WAITV(2); dot_row(13, 0); dot_row(13, 1);
    WAITV(1); dot_row(14, 0); dot_row(14, 1);
    WAITV(0); dot_row(15, 0); dot_row(15, 1);

    BAR();   // zp visible to all waves (lgkm-only; vmcnt already 0)

    // ---- phase-2 weights (wp dead now; disjoint register lifetime) ----
    float2 wr2[16];
    const float2* Wr2 = (const float2*)Wr;
#pragma unroll
    for (int d = 0; d < 16; ++d) wr2[d] = Wr2[d * 256 + tid];
    const float2 br2v = ((const float2*)br)[tid];

    // ============ Phase 2: reduce + recon (BARRIER-FREE) ============
    uint32_t ambmask = 0;          // block-uniform: built from ballots only
#pragma unroll 2
    for (int r = 0; r < TILE; ++r) {
        const float4 q0 = *(const float4*)&zp[r][dg][0];
        const float4 q1 = *(const float4*)&zp[r][dg][4];
        const float  z  = ((q0.x + q0.y) + (q0.z + q0.w))
                        + ((q1.x + q1.y) + (q1.z + q1.w)) + bpf;

        if (__ballot(fabsf(z) < TAU)) ambmask |= (1u << r);

        const unsigned long long bits = __ballot(z >= 0.0f);
        const int m = (int)(bits & 0xFFFFull);   // uniform, in SGPR

        float ox = br2v.x, oy = br2v.y;
#pragma unroll
        for (int d = 0; d < 16; ++d) {
            const float s = ((m >> d) & 1) ? 1.0f : -1.0f;
            ox = fmaf(s, wr2[d].x, ox);
            oy = fmaf(s, wr2[d].y, oy);
        }
        ((float2*)out)[(size_t)(row0 + r) * 256 + tid] = make_float2(ox, oy);
    }

    // ===== Fixup: rare exact-f64 redo; uniform loop => matched barriers =====
#pragma unroll 1
    while (ambmask) {
        const int r = __ffs(ambmask) - 1;
        ambmask &= ambmask - 1;
        const int row = row0 + r;

        const float* xp = x + (size_t)row * 512 + w * 128 + cg * 4;
        double ad = 0.0;
#pragma unroll
        for (int j = 0; j < 8; ++j) {
            const float4 xf = *(const float4*)(xp + j * 16);
#pragma unroll
            for (int e = 0; e < 4; ++e) {
                const float wpe = Wp[(w * 128 + j * 16 + cg * 4 + e) * 16 + dg];
                const float xe  = e == 0 ? xf.x : e == 1 ? xf.y
                               : e == 2 ? xf.z : xf.w;
                ad = fma((double)xe, (double)wpe, ad);
            }
        }
        ad += __shfl_xor(ad, 16, 64);
        ad += __shfl_xor(ad, 32, 64);
        if (cg == 0) zb64[dg][w] = ad;
        BAR();
        const double zd = (zb64[dg][0] + zb64[dg][1])
                        + (zb64[dg][2] + zb64[dg][3]) + bpd;
        BAR();   // all reads retired before next fixup row's rewrite

        const unsigned long long bits = __ballot(zd >= 0.0);
        const int m = (int)(bits & 0xFFFFull);
        float ox = br2v.x, oy = br2v.y;
#pragma unroll
        for (int d = 0; d < 16; ++d) {
            const float s = ((m >> d) & 1) ? 1.0f : -1.0f;
            ox = fmaf(s, wr2[d].x, ox);
            oy = fmaf(s, wr2[d].y, oy);
        }
        ((float2*)out)[(size_t)row * 256 + tid] = make_float2(ox, oy);
    }
}

extern "C" void kernel_launch(void* const* d_in, const int* in_sizes, int n_in,
                              void* d_out, int out_size, void* d_ws, size_t ws_size,
                              hipStream_t stream) {
    const float* x  = (const float*)d_in[0];
    const float* Wp = (const float*)d_in[1];
    const float* bp = (const float*)d_in[2];
    const float* Wr = (const float*)d_in[3];
    const float* br = (const float*)d_in[4];
    float* out = (float*)d_out;

    bsq_fused<<<BLOCKS, 256, 0, stream>>>(x, Wp, bp, Wr, br, out);
}